// Round 8
// baseline (213.311 us; speedup 1.0000x reference)
//
#include <hip/hip_runtime.h>

#define NLAYER 7
#define IMGB 16384          // bytes per weight-layer image: A[n][k] fp8, plain row-major
#define WSCALE 16.0f        // weights stored x16 (e4m3 subnormal protection)

typedef __attribute__((ext_vector_type(2))) float float2v;
typedef __attribute__((ext_vector_type(4))) float float4v;
typedef __attribute__((ext_vector_type(4))) unsigned int uint4v;
typedef __attribute__((ext_vector_type(8))) int int8v;
typedef unsigned long long u64;

__device__ __forceinline__ float2v pk_fma(float2v a, float2v b, float2v c){
  return __builtin_elementwise_fma(a, b, c);
}
__device__ __forceinline__ float2v lo2(float4v v){ return (float2v){v[0], v[1]}; }
__device__ __forceinline__ float2v hi2(float4v v){ return (float2v){v[2], v[3]}; }

// pack 4 f32 -> 4 fp8 e4m3 bytes (ascending)
__device__ __forceinline__ unsigned pk4fp8(float v0, float v1, float v2, float v3){
  int w = __builtin_amdgcn_cvt_pk_fp8_f32(v0, v1, 0, false);
  w = __builtin_amdgcn_cvt_pk_fp8_f32(v2, v3, w, true);
  return (unsigned)w;
}
template<bool HI>
__device__ __forceinline__ float2v up2(unsigned w){
  return __builtin_amdgcn_cvt_pk_f32_fp8((int)w, HI);
}
// MX-scaled MFMA, K=128, FMT=fp8 e4m3 both operands, scales = 1.0 (E8M0 0x7F)
__device__ __forceinline__ float4v mfma128(int8v a, int8v b){
  return __builtin_amdgcn_mfma_scale_f32_16x16x128_f8f6f4(
      a, b, (float4v){0.f,0.f,0.f,0.f}, 0, 0, 0, 0x7F7F7F7F, 0, 0x7F7F7F7F);
}
// P16 = 16*Phi(z) (cubic Taylor), gp16 = 16*gelu'(z)
__device__ __forceinline__ void act2(float2v z, float2v& P16, float2v& gp16){
  const float2v c1v  = {6.3830764862829235f, 6.3830764862829235f};
  const float2v c3v  = {-1.0638460810704874f, -1.0638460810704874f};
  const float2v c33v = {-3.1915382432114624f, -3.1915382432114624f};
  const float2v v8   = {8.f, 8.f};
  float2v z2 = z * z;
  float2v u  = pk_fma(z2, c3v, c1v);
  P16 = pk_fma(z, u, v8);
  float2v Pd = pk_fma(z2, c33v, c1v);
  gp16 = pk_fma(z, Pd, P16);
}

// B operand: 4 swizzled b64 chunks = k-bytes 32q..32q+31 of one element's LDS row
__device__ __forceinline__ int8v ld_b(const unsigned char* row, int q, int m0){
  u64 x0 = *(const u64*)(row + (((4*q+0) ^ m0)*8));
  u64 x1 = *(const u64*)(row + (((4*q+1) ^ m0)*8));
  u64 x2 = *(const u64*)(row + (((4*q+2) ^ m0)*8));
  u64 x3 = *(const u64*)(row + (((4*q+3) ^ m0)*8));
  int8v v;
  v[0]=(int)x0; v[1]=(int)(x0>>32);
  v[2]=(int)x1; v[3]=(int)(x1>>32);
  v[4]=(int)x2; v[5]=(int)(x2>>32);
  v[6]=(int)x3; v[7]=(int)(x3>>32);
  return v;
}
// A operand: 32 contiguous bytes from the plain global image (2x dwordx4)
__device__ __forceinline__ int8v ld_a(const unsigned char* p){
  uint4v a0 = *(const uint4v*)(p);
  uint4v a1 = *(const uint4v*)(p + 16);
  int8v v;
  v[0]=(int)a0[0]; v[1]=(int)a0[1]; v[2]=(int)a0[2]; v[3]=(int)a0[3];
  v[4]=(int)a1[0]; v[5]=(int)a1[1]; v[6]=(int)a1[2]; v[7]=(int)a1[3];
  return v;
}

// ---- prep: Wh fp32 [side][term][L][k][n] -> fp8 image [net][L][n][k] (plain), W*16 ----
__global__ __launch_bounds__(256)
void prep_weights(const float* __restrict__ lWh,
                  const float* __restrict__ rWh,
                  unsigned char* __restrict__ wbf)
{
  __shared__ __align__(16) unsigned char T[IMGB];
  const int b = blockIdx.x;               // net*7 + L
  const int net = b / NLAYER, L = b % NLAYER;
  const int side = net >> 1, term = net & 1;
  const float* src = (side ? rWh : lWh) + (size_t)((term*NLAYER + L)*128)*128;
  const int t = threadIdx.x;
  {
    const int k = t >> 1, n0 = (t & 1)*64;
    const float* row = src + k*128 + n0;
    #pragma unroll
    for (int c4 = 0; c4 < 4; ++c4){
      float4v f0 = *(const float4v*)(row + c4*16);
      float4v f1 = *(const float4v*)(row + c4*16 + 4);
      float4v f2 = *(const float4v*)(row + c4*16 + 8);
      float4v f3 = *(const float4v*)(row + c4*16 + 12);
      uint4v wv = { pk4fp8(f0[0]*WSCALE, f0[1]*WSCALE, f0[2]*WSCALE, f0[3]*WSCALE),
                    pk4fp8(f1[0]*WSCALE, f1[1]*WSCALE, f1[2]*WSCALE, f1[3]*WSCALE),
                    pk4fp8(f2[0]*WSCALE, f2[1]*WSCALE, f2[2]*WSCALE, f2[3]*WSCALE),
                    pk4fp8(f3[0]*WSCALE, f3[1]*WSCALE, f3[2]*WSCALE, f3[3]*WSCALE) };
      *(uint4v*)&T[k*128 + n0 + c4*16] = wv;
    }
  }
  __syncthreads();
  {
    const int n = t >> 1, c0 = (t & 1)*8;
    unsigned char* dst = wbf + ((size_t)b << 14) + n*128;
    #pragma unroll
    for (int c = 0; c < 8; ++c){
      const int kc = (c0 + c)*8;
      u64 v = 0;
      #pragma unroll
      for (int j = 0; j < 8; ++j)
        v |= (u64)T[(kc + j)*128 + n] << (8*j);
      *(u64*)(dst + (c0 + c)*8) = v;
    }
  }
}

__global__ __launch_bounds__(256, 4)
void sympl_main(const float* __restrict__ X,
                const float* __restrict__ lW0, const float* __restrict__ lb0,
                const float* __restrict__ lbh, const float* __restrict__ lWo,
                const float* __restrict__ rW0, const float* __restrict__ rb0,
                const float* __restrict__ rbh, const float* __restrict__ rWo,
                const int* __restrict__ lidx, const int* __restrict__ ridx,
                const unsigned char* __restrict__ wbf,
                float* __restrict__ out)
{
  // double-buffered activations; each buf: rows 0-31 S_h, rows 32-63 S_d
  // element row e, byte-chunk c: addr = e*128 + (c ^ (e&15))*8
  __shared__ __align__(16) unsigned char sH[2][8192];

  const int tid  = threadIdx.x;
  const int lane = tid & 63;
  const int w    = tid >> 6;
  const int m0   = lane & 15;
  const int q    = lane >> 4;
  const int col  = blockIdx.y;
  const int e0   = blockIdx.x * 32;
  const int r    = tid >> 3;       // element 0..31 (8 threads each)
  const int sg   = tid & 7;
  const int rs   = r & 15;

  const int lt = (lidx[0] == col) ? 0 : 1;
  const int rt = (ridx[0] == col) ? 0 : 1;

  float qv = X[(e0 + r)*4 + col];
  float pv = X[(e0 + r)*4 + 2 + col];

  const float dt = 0.1f;
  const float C0 = 0.6756035959798289f, C1 = -0.17560359597982883f;
  const float D0 = 1.3512071919596578f, D1 = -1.7024143839193153f;
  // fold 1/(16*4^7) = 1/262144 (final S_d scale) into the step coefficients
  const float is = 1.0f / 262144.0f;
  const float coefs[7] = { C0*dt*is, -D0*dt*is, C1*dt*is, -D1*dt*is,
                           C1*dt*is, -D0*dt*is, C0*dt*is };

  const float2v inv256v = {1.f/256.f, 1.f/256.f};
  const float2v inv64v  = {1.f/64.f, 1.f/64.f};

  for (int ev = 0; ev < 7; ++ev){
    const bool isT = !(ev & 1);
    const int  term = isT ? rt : lt;
    const float* W0p = (isT ? rW0 : lW0) + term*128;
    const float* b0p = (isT ? rb0 : lb0) + term*128;
    const float* bhp = (isT ? rbh : lbh) + term*NLAYER*128;
    const float* Wop = (isT ? rWo : lWo) + term*128;
    const unsigned char* wimg = wbf + (size_t)(((isT ? 2 : 0) + term)*NLAYER)*IMGB;

    // ---- layer 0 -> sH[0]: S_h = 16*gelu(z), S_d = 16*gelu'(z)*w, z = x*w+b ----
    {
      const float x = isT ? pv : qv;
      const float2v xv = {x, x};
      unsigned char* pH = sH[0] + r*128;
      unsigned char* pD = pH + 4096;
      #pragma unroll
      for (int c = 0; c < 2; ++c){
        int n0 = sg*16 + c*8;
        float4v wa = *(const float4v*)(W0p + n0);
        float4v wb = *(const float4v*)(W0p + n0 + 4);
        float4v ba = *(const float4v*)(b0p + n0);
        float4v bb = *(const float4v*)(b0p + n0 + 4);
        float2v zp[4] = { pk_fma(xv, lo2(wa), lo2(ba)), pk_fma(xv, hi2(wa), hi2(ba)),
                          pk_fma(xv, lo2(wb), lo2(bb)), pk_fma(xv, hi2(wb), hi2(bb)) };
        float2v wp[4] = { lo2(wa), hi2(wa), lo2(wb), hi2(wb) };
        float Sh[8], Sd[8];
        #pragma unroll
        for (int pp = 0; pp < 4; ++pp){
          float2v P16, gp16; act2(zp[pp], P16, gp16);
          float2v h = zp[pp] * P16;
          float2v d = gp16 * wp[pp];
          Sh[pp*2] = h[0]; Sh[pp*2+1] = h[1];
          Sd[pp*2] = d[0]; Sd[pp*2+1] = d[1];
        }
        u64 hv = (u64)pk4fp8(Sh[0],Sh[1],Sh[2],Sh[3]) | ((u64)pk4fp8(Sh[4],Sh[5],Sh[6],Sh[7]) << 32);
        u64 dv = (u64)pk4fp8(Sd[0],Sd[1],Sd[2],Sd[3]) | ((u64)pk4fp8(Sd[4],Sd[5],Sd[6],Sd[7]) << 32);
        int off = ((2*sg + c) ^ rs) * 8;
        *(u64*)(pH + off) = hv;
        *(u64*)(pD + off) = dv;
      }
    }
    __syncthreads();

    // ---- hidden layers: weights from global (L1/L2), one barrier per layer ----
    #pragma unroll
    for (int L = 0; L < NLAYER; ++L){
      const unsigned char* img = wimg + (size_t)L*IMGB;
      const unsigned char* br = sH[L & 1] + m0*128;
      unsigned char* bw = sH[(L+1) & 1];

      int8v b00 = ld_b(br,        q, m0);   // g0, h
      int8v b01 = ld_b(br + 4096, q, m0);   // g0, d
      int8v b10 = ld_b(br + 2048, q, m0);   // g1, h
      int8v b11 = ld_b(br + 6144, q, m0);   // g1, d

      float4v acc[2][2][2];
      #pragma unroll
      for (int t = 0; t < 2; ++t){
        const int I = 2*w + t;
        int8v a = ld_a(img + (I*16 + m0)*128 + q*32);
        acc[t][0][0] = mfma128(a, b00);
        acc[t][0][1] = mfma128(a, b01);
        acc[t][1][0] = mfma128(a, b10);
        acc[t][1][1] = mfma128(a, b11);
      }

      // epilogue -> other buffer
      const float* bias = bhp + L*128;
      const bool last = (L == NLAYER-1);
      #pragma unroll
      for (int t = 0; t < 2; ++t){
        const int I = 2*w + t;
        float4v bv = *(const float4v*)(bias + I*16 + q*4);
        const int off = ((2*I + (q >> 1)) ^ m0) * 8 + (q & 1) * 4;
        #pragma unroll
        for (int gg = 0; gg < 2; ++gg){
          float2v za = pk_fma(lo2(acc[t][gg][0]), inv256v, lo2(bv));
          float2v zb = pk_fma(hi2(acc[t][gg][0]), inv256v, hi2(bv));
          float2v ta = lo2(acc[t][gg][1]) * inv64v;
          float2v tb = hi2(acc[t][gg][1]) * inv64v;
          float2v Pa, ga, Pb, gb;
          act2(za, Pa, ga);
          act2(zb, Pb, gb);
          float2v da = ga * ta, db = gb * tb;
          unsigned char* base = bw + (gg*16 + m0)*128;
          if (!last){
            float2v ha = za * Pa, hb = zb * Pb;
            *(unsigned*)(base + off) = pk4fp8(ha[0], ha[1], hb[0], hb[1]);
          }
          *(unsigned*)(base + 4096 + off) = pk4fp8(da[0], da[1], db[0], db[1]);
        }
      }
      __syncthreads();   // sH[(L+1)&1] ready for next layer's B reads
    }

    // ---- reduce: s_raw = S_d7 . Wo (= 262144 * s); S_d7 is in sH[1] ----
    {
      const unsigned char* pD = sH[1] + 4096 + r*128;
      float2v sv = {0.f, 0.f};
      #pragma unroll
      for (int c = 0; c < 2; ++c){
        u64 dv8 = *(const u64*)(pD + ((2*sg + c) ^ rs) * 8);
        unsigned wlo = (unsigned)dv8, whi = (unsigned)(dv8 >> 32);
        float4v woa = *(const float4v*)(Wop + sg*16 + c*8);
        float4v wob = *(const float4v*)(Wop + sg*16 + c*8 + 4);
        sv = pk_fma(up2<false>(wlo), lo2(woa), sv);
        sv = pk_fma(up2<true>(wlo),  hi2(woa), sv);
        sv = pk_fma(up2<false>(whi), lo2(wob), sv);
        sv = pk_fma(up2<true>(whi),  hi2(wob), sv);
      }
      float s = sv[0] + sv[1];
      s += __shfl_xor(s, 1);
      s += __shfl_xor(s, 2);
      s += __shfl_xor(s, 4);
      if (isT) qv += coefs[ev] * s;
      else     pv += coefs[ev] * s;
    }
    // no barrier needed: next L0 writes sH[0] (last read before this eval's
    // final barrier); reduce reads sH[1], next written only after next L0 barrier.
  }

  if (sg == 0){
    out[(e0 + r)*4 + col]     = qv;
    out[(e0 + r)*4 + 2 + col] = pv;
  }
}

extern "C" void kernel_launch(void* const* d_in, const int* in_sizes, int n_in,
                              void* d_out, int out_size, void* d_ws, size_t ws_size,
                              hipStream_t stream)
{
  const float* X   = (const float*)d_in[0];
  const float* lW0 = (const float*)d_in[1];
  const float* lb0 = (const float*)d_in[2];
  const float* lWh = (const float*)d_in[3];
  const float* lbh = (const float*)d_in[4];
  const float* lWo = (const float*)d_in[5];
  const float* rW0 = (const float*)d_in[7];
  const float* rb0 = (const float*)d_in[8];
  const float* rWh = (const float*)d_in[9];
  const float* rbh = (const float*)d_in[10];
  const float* rWo = (const float*)d_in[11];
  const int*   li  = (const int*)d_in[13];
  const int*   ri  = (const int*)d_in[14];
  unsigned char* wbf = (unsigned char*)d_ws;   // 4*7*16384 B = 458752 B
  float* out = (float*)d_out;
  const int B = in_sizes[0] / 4;

  hipLaunchKernelGGL(prep_weights, dim3(4*NLAYER), dim3(256), 0, stream,
                     lWh, rWh, wbf);
  hipLaunchKernelGGL(sympl_main, dim3(B/32, 2), dim3(256), 0, stream,
                     X, lW0, lb0, lbh, lWo, rW0, rb0, rbh, rWo, li, ri, wbf, out);
}

// Round 9
// 204.749 us; speedup vs baseline: 1.0418x; 1.0418x over previous
//
#include <hip/hip_runtime.h>

#define NLAYER 7
#define IMGB 16384          // bytes per weight-layer image: A[n][k] fp8, plain row-major
#define WSCALE 16.0f        // weights stored x16 (e4m3 subnormal protection)

typedef __attribute__((ext_vector_type(2))) float float2v;
typedef __attribute__((ext_vector_type(4))) float float4v;
typedef __attribute__((ext_vector_type(4))) unsigned int uint4v;
typedef __attribute__((ext_vector_type(8))) int int8v;
typedef unsigned long long u64;

__device__ __forceinline__ float2v pk_fma(float2v a, float2v b, float2v c){
  return __builtin_elementwise_fma(a, b, c);
}
__device__ __forceinline__ float2v lo2(float4v v){ return (float2v){v[0], v[1]}; }
__device__ __forceinline__ float2v hi2(float4v v){ return (float2v){v[2], v[3]}; }

// pack 4 f32 -> 4 fp8 e4m3 bytes (ascending)
__device__ __forceinline__ unsigned pk4fp8(float v0, float v1, float v2, float v3){
  int w = __builtin_amdgcn_cvt_pk_fp8_f32(v0, v1, 0, false);
  w = __builtin_amdgcn_cvt_pk_fp8_f32(v2, v3, w, true);
  return (unsigned)w;
}
template<bool HI>
__device__ __forceinline__ float2v up2(unsigned w){
  return __builtin_amdgcn_cvt_pk_f32_fp8((int)w, HI);
}
// MX-scaled MFMA, K=128, FMT=fp8 e4m3 both operands, scales = 1.0 (E8M0 0x7F)
__device__ __forceinline__ float4v mfma128(int8v a, int8v b){
  return __builtin_amdgcn_mfma_scale_f32_16x16x128_f8f6f4(
      a, b, (float4v){0.f,0.f,0.f,0.f}, 0, 0, 0, 0x7F7F7F7F, 0, 0x7F7F7F7F);
}
// P16 = 16*Phi(z) (cubic Taylor), gp16 = 16*gelu'(z)
__device__ __forceinline__ void act2(float2v z, float2v& P16, float2v& gp16){
  const float2v c1v  = {6.3830764862829235f, 6.3830764862829235f};
  const float2v c3v  = {-1.0638460810704874f, -1.0638460810704874f};
  const float2v c33v = {-3.1915382432114624f, -3.1915382432114624f};
  const float2v v8   = {8.f, 8.f};
  float2v z2 = z * z;
  float2v u  = pk_fma(z2, c3v, c1v);
  P16 = pk_fma(z, u, v8);
  float2v Pd = pk_fma(z2, c33v, c1v);
  gp16 = pk_fma(z, Pd, P16);
}

// B operand: 4 swizzled b64 chunks = k-bytes 32q..32q+31 of one element's LDS row
__device__ __forceinline__ int8v ld_b(const unsigned char* row, int q, int m0){
  u64 x0 = *(const u64*)(row + (((4*q+0) ^ m0)*8));
  u64 x1 = *(const u64*)(row + (((4*q+1) ^ m0)*8));
  u64 x2 = *(const u64*)(row + (((4*q+2) ^ m0)*8));
  u64 x3 = *(const u64*)(row + (((4*q+3) ^ m0)*8));
  int8v v;
  v[0]=(int)x0; v[1]=(int)(x0>>32);
  v[2]=(int)x1; v[3]=(int)(x1>>32);
  v[4]=(int)x2; v[5]=(int)(x2>>32);
  v[6]=(int)x3; v[7]=(int)(x3>>32);
  return v;
}
// A operand: 32 contiguous bytes from the plain global image (2x dwordx4)
__device__ __forceinline__ int8v ld_a(const unsigned char* p){
  uint4v a0 = *(const uint4v*)(p);
  uint4v a1 = *(const uint4v*)(p + 16);
  int8v v;
  v[0]=(int)a0[0]; v[1]=(int)a0[1]; v[2]=(int)a0[2]; v[3]=(int)a0[3];
  v[4]=(int)a1[0]; v[5]=(int)a1[1]; v[6]=(int)a1[2]; v[7]=(int)a1[3];
  return v;
}

// ---- prep: Wh fp32 [side][term][L][k][n] -> fp8 image [net][L][n][k] (plain), W*16 ----
__global__ __launch_bounds__(256)
void prep_weights(const float* __restrict__ lWh,
                  const float* __restrict__ rWh,
                  unsigned char* __restrict__ wbf)
{
  __shared__ __align__(16) unsigned char T[IMGB];
  const int b = blockIdx.x;               // net*7 + L
  const int net = b / NLAYER, L = b % NLAYER;
  const int side = net >> 1, term = net & 1;
  const float* src = (side ? rWh : lWh) + (size_t)((term*NLAYER + L)*128)*128;
  const int t = threadIdx.x;
  {
    const int k = t >> 1, n0 = (t & 1)*64;
    const float* row = src + k*128 + n0;
    #pragma unroll
    for (int c4 = 0; c4 < 4; ++c4){
      float4v f0 = *(const float4v*)(row + c4*16);
      float4v f1 = *(const float4v*)(row + c4*16 + 4);
      float4v f2 = *(const float4v*)(row + c4*16 + 8);
      float4v f3 = *(const float4v*)(row + c4*16 + 12);
      uint4v wv = { pk4fp8(f0[0]*WSCALE, f0[1]*WSCALE, f0[2]*WSCALE, f0[3]*WSCALE),
                    pk4fp8(f1[0]*WSCALE, f1[1]*WSCALE, f1[2]*WSCALE, f1[3]*WSCALE),
                    pk4fp8(f2[0]*WSCALE, f2[1]*WSCALE, f2[2]*WSCALE, f2[3]*WSCALE),
                    pk4fp8(f3[0]*WSCALE, f3[1]*WSCALE, f3[2]*WSCALE, f3[3]*WSCALE) };
      *(uint4v*)&T[k*128 + n0 + c4*16] = wv;
    }
  }
  __syncthreads();
  {
    const int n = t >> 1, c0 = (t & 1)*8;
    unsigned char* dst = wbf + ((size_t)b << 14) + n*128;
    #pragma unroll
    for (int c = 0; c < 8; ++c){
      const int kc = (c0 + c)*8;
      u64 v = 0;
      #pragma unroll
      for (int j = 0; j < 8; ++j)
        v |= (u64)T[(kc + j)*128 + n] << (8*j);
      *(u64*)(dst + (c0 + c)*8) = v;
    }
  }
}

__global__ __launch_bounds__(256, 4)
void sympl_main(const float* __restrict__ X,
                const float* __restrict__ lW0, const float* __restrict__ lb0,
                const float* __restrict__ lbh, const float* __restrict__ lWo,
                const float* __restrict__ rW0, const float* __restrict__ rb0,
                const float* __restrict__ rbh, const float* __restrict__ rWo,
                const int* __restrict__ lidx, const int* __restrict__ ridx,
                const unsigned char* __restrict__ wbf,
                float* __restrict__ out)
{
  // double-buffered activations; each buf: rows 0-31 S_h, rows 32-63 S_d
  // element row e, byte-chunk c: addr = e*128 + (c ^ (e&15))*8
  __shared__ __align__(16) unsigned char sH[2][8192];

  const int tid  = threadIdx.x;
  const int lane = tid & 63;
  const int w    = tid >> 6;
  const int m0   = lane & 15;
  const int q    = lane >> 4;
  const int col  = blockIdx.y;
  const int e0   = blockIdx.x * 32;
  const int r    = tid >> 3;       // element 0..31 (8 threads each)
  const int sg   = tid & 7;
  const int rs   = r & 15;

  const int lt = (lidx[0] == col) ? 0 : 1;
  const int rt = (ridx[0] == col) ? 0 : 1;

  float qv = X[(e0 + r)*4 + col];
  float pv = X[(e0 + r)*4 + 2 + col];

  const float dt = 0.1f;
  const float C0 = 0.6756035959798289f, C1 = -0.17560359597982883f;
  const float D0 = 1.3512071919596578f, D1 = -1.7024143839193153f;
  // fold 1/(16*4^7) = 1/262144 (final S_d scale) into the step coefficients
  const float is = 1.0f / 262144.0f;
  const float coefs[7] = { C0*dt*is, -D0*dt*is, C1*dt*is, -D1*dt*is,
                           C1*dt*is, -D0*dt*is, C0*dt*is };

  const float2v inv256v = {1.f/256.f, 1.f/256.f};
  const float2v inv64v  = {1.f/64.f, 1.f/64.f};

  // per-wave operand offsets (loop-invariant)
  const int aoff0 = ((2*w + 0)*16 + m0)*128 + q*32;
  const int aoff1 = ((2*w + 1)*16 + m0)*128 + q*32;

  // prefetched A-frags + biases for the upcoming hidden layer (straightline SSA)
  int8v   pa0, pa1;
  float4v pb0, pb1;

  for (int ev = 0; ev < 7; ++ev){
    const bool isT = !(ev & 1);
    const int  term = isT ? rt : lt;
    const float* W0p = (isT ? rW0 : lW0) + term*128;
    const float* b0p = (isT ? rb0 : lb0) + term*128;
    const float* bhp = (isT ? rbh : lbh) + term*NLAYER*128;
    const float* Wop = (isT ? rWo : lWo) + term*128;
    const unsigned char* wimg = wbf + (size_t)(((isT ? 2 : 0) + term)*NLAYER)*IMGB;

    // prefetch L=0 operands (hidden by layer-0 compute + barrier)
    pa0 = ld_a(wimg + aoff0);
    pa1 = ld_a(wimg + aoff1);
    pb0 = *(const float4v*)(bhp + (2*w + 0)*16 + q*4);
    pb1 = *(const float4v*)(bhp + (2*w + 1)*16 + q*4);

    // ---- layer 0 -> sH[0]: S_h = 16*gelu(z), S_d = 16*gelu'(z)*w, z = x*w+b ----
    {
      const float x = isT ? pv : qv;
      const float2v xv = {x, x};
      unsigned char* pH = sH[0] + r*128;
      unsigned char* pD = pH + 4096;
      #pragma unroll
      for (int c = 0; c < 2; ++c){
        int n0 = sg*16 + c*8;
        float4v wa = *(const float4v*)(W0p + n0);
        float4v wb = *(const float4v*)(W0p + n0 + 4);
        float4v ba = *(const float4v*)(b0p + n0);
        float4v bb = *(const float4v*)(b0p + n0 + 4);
        float2v zp[4] = { pk_fma(xv, lo2(wa), lo2(ba)), pk_fma(xv, hi2(wa), hi2(ba)),
                          pk_fma(xv, lo2(wb), lo2(bb)), pk_fma(xv, hi2(wb), hi2(bb)) };
        float2v wp[4] = { lo2(wa), hi2(wa), lo2(wb), hi2(wb) };
        float Sh[8], Sd[8];
        #pragma unroll
        for (int pp = 0; pp < 4; ++pp){
          float2v P16, gp16; act2(zp[pp], P16, gp16);
          float2v h = zp[pp] * P16;
          float2v d = gp16 * wp[pp];
          Sh[pp*2] = h[0]; Sh[pp*2+1] = h[1];
          Sd[pp*2] = d[0]; Sd[pp*2+1] = d[1];
        }
        u64 hv = (u64)pk4fp8(Sh[0],Sh[1],Sh[2],Sh[3]) | ((u64)pk4fp8(Sh[4],Sh[5],Sh[6],Sh[7]) << 32);
        u64 dv = (u64)pk4fp8(Sd[0],Sd[1],Sd[2],Sd[3]) | ((u64)pk4fp8(Sd[4],Sd[5],Sd[6],Sd[7]) << 32);
        int off = ((2*sg + c) ^ rs) * 8;
        *(u64*)(pH + off) = hv;
        *(u64*)(pD + off) = dv;
      }
    }
    __syncthreads();

    // ---- hidden layers: A/bias register-prefetched one layer ahead ----
    #pragma unroll
    for (int L = 0; L < NLAYER; ++L){
      const unsigned char* br = sH[L & 1] + m0*128;
      unsigned char* bw = sH[(L+1) & 1];

      int8v b00 = ld_b(br,        q, m0);   // g0, h
      int8v b01 = ld_b(br + 4096, q, m0);   // g0, d
      int8v b10 = ld_b(br + 2048, q, m0);   // g1, h
      int8v b11 = ld_b(br + 6144, q, m0);   // g1, d

      float4v acc[2][2][2];
      acc[0][0][0] = mfma128(pa0, b00);
      acc[0][0][1] = mfma128(pa0, b01);
      acc[0][1][0] = mfma128(pa0, b10);
      acc[0][1][1] = mfma128(pa0, b11);
      acc[1][0][0] = mfma128(pa1, b00);
      acc[1][0][1] = mfma128(pa1, b01);
      acc[1][1][0] = mfma128(pa1, b10);
      acc[1][1][1] = mfma128(pa1, b11);

      float4v bv0 = pb0, bv1 = pb1;

      // prefetch next layer's A/bias (loads fly during epilogue + barrier)
      if (L < NLAYER-1){
        const unsigned char* nimg = wimg + (size_t)(L+1)*IMGB;
        pa0 = ld_a(nimg + aoff0);
        pa1 = ld_a(nimg + aoff1);
        pb0 = *(const float4v*)(bhp + (L+1)*128 + (2*w + 0)*16 + q*4);
        pb1 = *(const float4v*)(bhp + (L+1)*128 + (2*w + 1)*16 + q*4);
      }

      // epilogue -> other buffer
      const bool last = (L == NLAYER-1);
      #pragma unroll
      for (int t = 0; t < 2; ++t){
        const int I = 2*w + t;
        float4v bv = t ? bv1 : bv0;
        const int off = ((2*I + (q >> 1)) ^ m0) * 8 + (q & 1) * 4;
        #pragma unroll
        for (int gg = 0; gg < 2; ++gg){
          float2v za = pk_fma(lo2(acc[t][gg][0]), inv256v, lo2(bv));
          float2v zb = pk_fma(hi2(acc[t][gg][0]), inv256v, hi2(bv));
          float2v ta = lo2(acc[t][gg][1]) * inv64v;
          float2v tb = hi2(acc[t][gg][1]) * inv64v;
          float2v Pa, ga, Pb, gb;
          act2(za, Pa, ga);
          act2(zb, Pb, gb);
          float2v da = ga * ta, db = gb * tb;
          unsigned char* base = bw + (gg*16 + m0)*128;
          if (!last){
            float2v ha = za * Pa, hb = zb * Pb;
            *(unsigned*)(base + off) = pk4fp8(ha[0], ha[1], hb[0], hb[1]);
          }
          *(unsigned*)(base + 4096 + off) = pk4fp8(da[0], da[1], db[0], db[1]);
        }
      }
      __syncthreads();   // sH[(L+1)&1] ready for next layer's B reads
    }

    // ---- reduce: s_raw = S_d7 . Wo (= 262144 * s); S_d7 is in sH[1] ----
    {
      const unsigned char* pD = sH[1] + 4096 + r*128;
      float2v sv = {0.f, 0.f};
      #pragma unroll
      for (int c = 0; c < 2; ++c){
        u64 dv8 = *(const u64*)(pD + ((2*sg + c) ^ rs) * 8);
        unsigned wlo = (unsigned)dv8, whi = (unsigned)(dv8 >> 32);
        float4v woa = *(const float4v*)(Wop + sg*16 + c*8);
        float4v wob = *(const float4v*)(Wop + sg*16 + c*8 + 4);
        sv = pk_fma(up2<false>(wlo), lo2(woa), sv);
        sv = pk_fma(up2<true>(wlo),  hi2(woa), sv);
        sv = pk_fma(up2<false>(whi), lo2(wob), sv);
        sv = pk_fma(up2<true>(whi),  hi2(wob), sv);
      }
      float s = sv[0] + sv[1];
      s += __shfl_xor(s, 1);
      s += __shfl_xor(s, 2);
      s += __shfl_xor(s, 4);
      if (isT) qv = fmaf(coefs[ev], s, qv);
      else     pv = fmaf(coefs[ev], s, pv);
    }
    // no barrier needed: next L0 writes sH[0] (last read before this eval's
    // final barrier); reduce reads sH[1], next written only after next L0 barrier.
  }

  if (sg == 0){
    out[(e0 + r)*4 + col]     = qv;
    out[(e0 + r)*4 + 2 + col] = pv;
  }
}

extern "C" void kernel_launch(void* const* d_in, const int* in_sizes, int n_in,
                              void* d_out, int out_size, void* d_ws, size_t ws_size,
                              hipStream_t stream)
{
  const float* X   = (const float*)d_in[0];
  const float* lW0 = (const float*)d_in[1];
  const float* lb0 = (const float*)d_in[2];
  const float* lWh = (const float*)d_in[3];
  const float* lbh = (const float*)d_in[4];
  const float* lWo = (const float*)d_in[5];
  const float* rW0 = (const float*)d_in[7];
  const float* rb0 = (const float*)d_in[8];
  const float* rWh = (const float*)d_in[9];
  const float* rbh = (const float*)d_in[10];
  const float* rWo = (const float*)d_in[11];
  const int*   li  = (const int*)d_in[13];
  const int*   ri  = (const int*)d_in[14];
  unsigned char* wbf = (unsigned char*)d_ws;   // 4*7*16384 B = 458752 B
  float* out = (float*)d_out;
  const int B = in_sizes[0] / 4;

  hipLaunchKernelGGL(prep_weights, dim3(4*NLAYER), dim3(256), 0, stream,
                     lWh, rWh, wbf);
  hipLaunchKernelGGL(sympl_main, dim3(B/32, 2), dim3(256), 0, stream,
                     X, lW0, lb0, lbh, lWo, rW0, rb0, rbh, rWo, li, ri, wbf, out);
}